// Round 6
// baseline (245.002 us; speedup 1.0000x reference)
//
#include <hip/hip_runtime.h>

typedef _Float16 f16;
typedef f16 half8 __attribute__((ext_vector_type(8)));
typedef float f32x16 __attribute__((ext_vector_type(16)));

#define BB 8
#define NN 8192
#define SETPTS (BB * NN)   // 65536 points per set
#define NPTS (2 * SETPTS)  // 131072 total points
#define TQ NPTS            // total queries

// ---------------- prep: build fp16-split MFMA operands ----------------
// A-rep (query):  per coord (h,l,h,l); tail (1,1,0,0)
// B-rep (ref):    per coord (H,H,L,L) of -2y; tail (yy_h,yy_l,0,0)
// products per coord: hH + lH + hL + lL = (h+l)(H+L)  [exact in fp32 accum]
__global__ __launch_bounds__(256) void chamfer_prep(
    const float* __restrict__ preds, const float* __restrict__ gts,
    float* __restrict__ yy, half8* __restrict__ Aq, half8* __restrict__ Bq) {
  int idx = blockIdx.x * 256 + threadIdx.x;  // 0..NPTS-1
  int s = idx >> 16;                         // set: 0=preds, 1=gts
  int off = idx & (SETPTS - 1);
  const float* src = s ? gts : preds;
  float x0 = src[off * 3 + 0], x1 = src[off * 3 + 1], x2 = src[off * 3 + 2];

  f16 h0 = (f16)x0; f16 l0 = (f16)(x0 - (float)h0);
  f16 h1 = (f16)x1; f16 l1 = (f16)(x1 - (float)h1);
  f16 h2 = (f16)x2; f16 l2 = (f16)(x2 - (float)h2);

  float Y0 = -2.f * x0, Y1 = -2.f * x1, Y2 = -2.f * x2;
  f16 H0 = (f16)Y0; f16 L0 = (f16)(Y0 - (float)H0);
  f16 H1 = (f16)Y1; f16 L1 = (f16)(Y1 - (float)H1);
  f16 H2 = (f16)Y2; f16 L2 = (f16)(Y2 - (float)H2);

  float yv = x0 * x0 + x1 * x1 + x2 * x2;
  f16 yh = (f16)yv; f16 yl = (f16)(yv - (float)yh);

  f16 one = (f16)1.f, zz = (f16)0.f;
  half8 A0 = {h0, l0, h0, l0, h1, l1, h1, l1};
  half8 A1 = {h2, l2, h2, l2, one, one, zz, zz};
  half8 B0 = {H0, H0, L0, L0, H1, H1, L1, L1};
  half8 B1 = {H2, H2, L2, L2, yh, yl, zz, zz};

  Aq[idx * 2 + 0] = A0; Aq[idx * 2 + 1] = A1;
  Bq[idx * 2 + 0] = B0; Bq[idx * 2 + 1] = B1;
  yy[idx] = yv;
}

// ---------------- main: MFMA distance tiles + running per-query min ------
// EXACT round-4 inner structure (known-good 46us @ 4 waves/SIMD); only the
// grid (R) and launch_bounds occupancy cap changed this round.
// Wave: 64 queries (2 A-frags). Block: 4 waves = 256 queries.
// Grid: dir(2) x b(8) x qb(32) x r(R).
// A layout (32x32x16): row=lane&31, k=(lane>>5)*8+e.
// C/D layout: col=lane&31, row=(reg&3)+8*(reg>>2)+4*(lane>>5).
template <int R>
__global__ __launch_bounds__(256, 8) void chamfer_mfma(
    const half8* __restrict__ Aq, const half8* __restrict__ Bq,
    float* __restrict__ partial) {
  constexpr int NSTEP = NN / R / 32;  // b-tiles per block
  int bi = blockIdx.x;
  int r = bi % R;
  int qb = (bi / R) % 32;
  int b = (bi / (R * 32)) % BB;
  int dir = bi / (R * 32 * BB);

  int tid = threadIdx.x;
  int wid = tid >> 6;
  int l = tid & 63;
  int l31 = l & 31;
  int lh = l >> 5;

  const half8* Ap =
      Aq + ((size_t)(dir * BB + b) * NN + qb * 256 + wid * 64) * 2;
  half8 a0 = Ap[l31 * 2 + lh];
  half8 a1 = Ap[(32 + l31) * 2 + lh];

  const half8* Bl = Bq +
                    ((size_t)((1 - dir) * BB + b) * NN + r * (NN / R)) * 2 +
                    l31 * 2 + lh;

  f32x16 zero;
#pragma unroll
  for (int i = 0; i < 16; ++i) zero[i] = 0.f;
  f32x16 run0, run1;
#pragma unroll
  for (int i = 0; i < 16; ++i) { run0[i] = 3.4e38f; run1[i] = 3.4e38f; }

  half8 bcur = Bl[0];
#pragma unroll 2
  for (int step = 0; step < NSTEP; ++step) {
    half8 bnext = Bl[(size_t)(((step + 1) & (NSTEP - 1)) * 64)];  // wraps
    f32x16 o0 = __builtin_amdgcn_mfma_f32_32x32x16_f16(a0, bcur, zero, 0, 0, 0);
    f32x16 o1 = __builtin_amdgcn_mfma_f32_32x32x16_f16(a1, bcur, zero, 0, 0, 0);
#pragma unroll
    for (int i = 0; i < 16; ++i) {
      run0[i] = fminf(run0[i], o0[i]);
      run1[i] = fminf(run1[i], o1[i]);
    }
    bcur = bnext;
  }

  // min over ref-columns (32 lanes within each half), write per-query
  size_t qflat = (size_t)(dir * BB + b) * NN + qb * 256 + wid * 64;
  float* pr = partial + (size_t)r * TQ + qflat;
#pragma unroll
  for (int i = 0; i < 16; ++i) {
    float v0 = run0[i], v1 = run1[i];
    v0 = fminf(v0, __shfl_xor(v0, 1));  v1 = fminf(v1, __shfl_xor(v1, 1));
    v0 = fminf(v0, __shfl_xor(v0, 2));  v1 = fminf(v1, __shfl_xor(v1, 2));
    v0 = fminf(v0, __shfl_xor(v0, 4));  v1 = fminf(v1, __shfl_xor(v1, 4));
    v0 = fminf(v0, __shfl_xor(v0, 8));  v1 = fminf(v1, __shfl_xor(v1, 8));
    v0 = fminf(v0, __shfl_xor(v0, 16)); v1 = fminf(v1, __shfl_xor(v1, 16));
    int row = (i & 3) + 8 * (i >> 2) + 4 * lh;
    if (l31 == i) {
      pr[row] = v0;
      pr[32 + row] = v1;
    }
  }
}

// ---------------- combine: min over R slices + query norm, block sum -----
template <int R>
__global__ __launch_bounds__(256) void chamfer_combine(
    const float* __restrict__ partial, const float* __restrict__ yy,
    float* __restrict__ bsums) {
  int q = blockIdx.x * 256 + threadIdx.x;
  float m = partial[q];
#pragma unroll
  for (int rr = 1; rr < R; ++rr) m = fminf(m, partial[(size_t)rr * TQ + q]);
  m += yy[q];
  __shared__ float s[256];
  s[threadIdx.x] = m;
  __syncthreads();
  for (int o = 128; o > 0; o >>= 1) {
    if (threadIdx.x < o) s[threadIdx.x] += s[threadIdx.x + o];
    __syncthreads();
  }
  if (threadIdx.x == 0) bsums[blockIdx.x] = s[0];
}

__global__ __launch_bounds__(256) void chamfer_final(
    const float* __restrict__ bsums, float* __restrict__ out, int n) {
  float v = 0.f;
  for (int i = threadIdx.x; i < n; i += 256) v += bsums[i];
  __shared__ float s[256];
  s[threadIdx.x] = v;
  __syncthreads();
  for (int o = 128; o > 0; o >>= 1) {
    if (threadIdx.x < o) s[threadIdx.x] += s[threadIdx.x + o];
    __syncthreads();
  }
  if (threadIdx.x == 0) out[0] = s[0];
}

extern "C" void kernel_launch(void* const* d_in, const int* in_sizes, int n_in,
                              void* d_out, int out_size, void* d_ws,
                              size_t ws_size, hipStream_t stream) {
  const float* preds = (const float*)d_in[0];
  const float* gts = (const float*)d_in[1];
  float* out = (float*)d_out;

  // ws layout (floats): partial[R*TQ] | bsums[1024] | yy[NPTS] | Aq | Bq
  size_t fixed = (size_t)1024 * 4 + (size_t)NPTS * 4 + (size_t)NPTS * 64;
  int R = (ws_size >= (size_t)4 * TQ * 4 + fixed) ? 4 : 2;

  float* partial = (float*)d_ws;
  float* bsums = partial + (size_t)R * TQ;
  float* yy = bsums + 1024;
  half8* Aq = (half8*)(yy + NPTS);
  half8* Bq = Aq + (size_t)NPTS * 2;

  chamfer_prep<<<NPTS / 256, 256, 0, stream>>>(preds, gts, yy, Aq, Bq);
  if (R == 4) {
    chamfer_mfma<4><<<2 * BB * 32 * 4, 256, 0, stream>>>(Aq, Bq, partial);
    chamfer_combine<4><<<TQ / 256, 256, 0, stream>>>(partial, yy, bsums);
  } else {
    chamfer_mfma<2><<<2 * BB * 32 * 2, 256, 0, stream>>>(Aq, Bq, partial);
    chamfer_combine<2><<<TQ / 256, 256, 0, stream>>>(partial, yy, bsums);
  }
  chamfer_final<<<1, 256, 0, stream>>>(bsums, out, TQ / 256);
}

// Round 7
// 60.877 us; speedup vs baseline: 4.0245x; 4.0245x over previous
//
#include <hip/hip_runtime.h>

typedef _Float16 f16;
typedef f16 half8 __attribute__((ext_vector_type(8)));
typedef float f32x16 __attribute__((ext_vector_type(16)));

#define BB 8
#define NN 8192
#define SETPTS (BB * NN)   // 65536 points per set
#define NPTS (2 * SETPTS)  // 131072 total points
#define TQ NPTS            // total queries

// ---------------- prep: build fp16-split MFMA operands ----------------
// A-rep (query):  per coord (h,l,h,l); tail (1,1,0,0)
// B-rep (ref):    per coord (H,H,L,L) of -2y; tail (yy_h,yy_l,0,0)
// products per coord: hH + lH + hL + lL = (h+l)(H+L)  [exact in fp32 accum]
__global__ __launch_bounds__(256) void chamfer_prep(
    const float* __restrict__ preds, const float* __restrict__ gts,
    float* __restrict__ yy, half8* __restrict__ Aq, half8* __restrict__ Bq) {
  int idx = blockIdx.x * 256 + threadIdx.x;  // 0..NPTS-1
  int s = idx >> 16;                         // set: 0=preds, 1=gts
  int off = idx & (SETPTS - 1);
  const float* src = s ? gts : preds;
  float x0 = src[off * 3 + 0], x1 = src[off * 3 + 1], x2 = src[off * 3 + 2];

  f16 h0 = (f16)x0; f16 l0 = (f16)(x0 - (float)h0);
  f16 h1 = (f16)x1; f16 l1 = (f16)(x1 - (float)h1);
  f16 h2 = (f16)x2; f16 l2 = (f16)(x2 - (float)h2);

  float Y0 = -2.f * x0, Y1 = -2.f * x1, Y2 = -2.f * x2;
  f16 H0 = (f16)Y0; f16 L0 = (f16)(Y0 - (float)H0);
  f16 H1 = (f16)Y1; f16 L1 = (f16)(Y1 - (float)H1);
  f16 H2 = (f16)Y2; f16 L2 = (f16)(Y2 - (float)H2);

  float yv = x0 * x0 + x1 * x1 + x2 * x2;
  f16 yh = (f16)yv; f16 yl = (f16)(yv - (float)yh);

  f16 one = (f16)1.f, zz = (f16)0.f;
  half8 A0 = {h0, l0, h0, l0, h1, l1, h1, l1};
  half8 A1 = {h2, l2, h2, l2, one, one, zz, zz};
  half8 B0 = {H0, H0, L0, L0, H1, H1, L1, L1};
  half8 B1 = {H2, H2, L2, L2, yh, yl, zz, zz};

  Aq[idx * 2 + 0] = A0; Aq[idx * 2 + 1] = A1;
  Bq[idx * 2 + 0] = B0; Bq[idx * 2 + 1] = B1;
  yy[idx] = yv;
}

// ---------------- main: MFMA distance tiles + running per-query min ------
// EXACT round-4 inner structure AND round-4 launch_bounds(256,4) (VGPR=48,
// no spill). Occupancy comes from the grid alone: R=4 -> 2048 blocks =
// 8 blocks/CU = 32 waves/CU.
// Wave: 64 queries (2 A-frags). Block: 4 waves = 256 queries.
// Grid: dir(2) x b(8) x qb(32) x r(R).
// A layout (32x32x16): row=lane&31, k=(lane>>5)*8+e.
// C/D layout: col=lane&31, row=(reg&3)+8*(reg>>2)+4*(lane>>5).
template <int R>
__global__ __launch_bounds__(256, 4) void chamfer_mfma(
    const half8* __restrict__ Aq, const half8* __restrict__ Bq,
    float* __restrict__ partial) {
  constexpr int NSTEP = NN / R / 32;  // b-tiles per block
  int bi = blockIdx.x;
  int r = bi % R;
  int qb = (bi / R) % 32;
  int b = (bi / (R * 32)) % BB;
  int dir = bi / (R * 32 * BB);

  int tid = threadIdx.x;
  int wid = tid >> 6;
  int l = tid & 63;
  int l31 = l & 31;
  int lh = l >> 5;

  const half8* Ap =
      Aq + ((size_t)(dir * BB + b) * NN + qb * 256 + wid * 64) * 2;
  half8 a0 = Ap[l31 * 2 + lh];
  half8 a1 = Ap[(32 + l31) * 2 + lh];

  const half8* Bl = Bq +
                    ((size_t)((1 - dir) * BB + b) * NN + r * (NN / R)) * 2 +
                    l31 * 2 + lh;

  f32x16 zero;
#pragma unroll
  for (int i = 0; i < 16; ++i) zero[i] = 0.f;
  f32x16 run0, run1;
#pragma unroll
  for (int i = 0; i < 16; ++i) { run0[i] = 3.4e38f; run1[i] = 3.4e38f; }

  half8 bcur = Bl[0];
#pragma unroll 2
  for (int step = 0; step < NSTEP; ++step) {
    half8 bnext = Bl[(size_t)(((step + 1) & (NSTEP - 1)) * 64)];  // wraps
    f32x16 o0 = __builtin_amdgcn_mfma_f32_32x32x16_f16(a0, bcur, zero, 0, 0, 0);
    f32x16 o1 = __builtin_amdgcn_mfma_f32_32x32x16_f16(a1, bcur, zero, 0, 0, 0);
#pragma unroll
    for (int i = 0; i < 16; ++i) {
      run0[i] = fminf(run0[i], o0[i]);
      run1[i] = fminf(run1[i], o1[i]);
    }
    bcur = bnext;
  }

  // min over ref-columns (32 lanes within each half), write per-query
  size_t qflat = (size_t)(dir * BB + b) * NN + qb * 256 + wid * 64;
  float* pr = partial + (size_t)r * TQ + qflat;
#pragma unroll
  for (int i = 0; i < 16; ++i) {
    float v0 = run0[i], v1 = run1[i];
    v0 = fminf(v0, __shfl_xor(v0, 1));  v1 = fminf(v1, __shfl_xor(v1, 1));
    v0 = fminf(v0, __shfl_xor(v0, 2));  v1 = fminf(v1, __shfl_xor(v1, 2));
    v0 = fminf(v0, __shfl_xor(v0, 4));  v1 = fminf(v1, __shfl_xor(v1, 4));
    v0 = fminf(v0, __shfl_xor(v0, 8));  v1 = fminf(v1, __shfl_xor(v1, 8));
    v0 = fminf(v0, __shfl_xor(v0, 16)); v1 = fminf(v1, __shfl_xor(v1, 16));
    int row = (i & 3) + 8 * (i >> 2) + 4 * lh;
    if (l31 == i) {
      pr[row] = v0;
      pr[32 + row] = v1;
    }
  }
}

// ---------------- combine: min over R slices + query norm, block sum -----
template <int R>
__global__ __launch_bounds__(256) void chamfer_combine(
    const float* __restrict__ partial, const float* __restrict__ yy,
    float* __restrict__ bsums) {
  int q = blockIdx.x * 256 + threadIdx.x;
  float m = partial[q];
#pragma unroll
  for (int rr = 1; rr < R; ++rr) m = fminf(m, partial[(size_t)rr * TQ + q]);
  m += yy[q];
  __shared__ float s[256];
  s[threadIdx.x] = m;
  __syncthreads();
  for (int o = 128; o > 0; o >>= 1) {
    if (threadIdx.x < o) s[threadIdx.x] += s[threadIdx.x + o];
    __syncthreads();
  }
  if (threadIdx.x == 0) bsums[blockIdx.x] = s[0];
}

__global__ __launch_bounds__(256) void chamfer_final(
    const float* __restrict__ bsums, float* __restrict__ out, int n) {
  float v = 0.f;
  for (int i = threadIdx.x; i < n; i += 256) v += bsums[i];
  __shared__ float s[256];
  s[threadIdx.x] = v;
  __syncthreads();
  for (int o = 128; o > 0; o >>= 1) {
    if (threadIdx.x < o) s[threadIdx.x] += s[threadIdx.x + o];
    __syncthreads();
  }
  if (threadIdx.x == 0) out[0] = s[0];
}

extern "C" void kernel_launch(void* const* d_in, const int* in_sizes, int n_in,
                              void* d_out, int out_size, void* d_ws,
                              size_t ws_size, hipStream_t stream) {
  const float* preds = (const float*)d_in[0];
  const float* gts = (const float*)d_in[1];
  float* out = (float*)d_out;

  // ws layout (floats): partial[R*TQ] | bsums[1024] | yy[NPTS] | Aq | Bq
  size_t fixed = (size_t)1024 * 4 + (size_t)NPTS * 4 + (size_t)NPTS * 64;
  int R = (ws_size >= (size_t)4 * TQ * 4 + fixed) ? 4 : 2;

  float* partial = (float*)d_ws;
  float* bsums = partial + (size_t)R * TQ;
  float* yy = bsums + 1024;
  half8* Aq = (half8*)(yy + NPTS);
  half8* Bq = Aq + (size_t)NPTS * 2;

  chamfer_prep<<<NPTS / 256, 256, 0, stream>>>(preds, gts, yy, Aq, Bq);
  if (R == 4) {
    chamfer_mfma<4><<<2 * BB * 32 * 4, 256, 0, stream>>>(Aq, Bq, partial);
    chamfer_combine<4><<<TQ / 256, 256, 0, stream>>>(partial, yy, bsums);
  } else {
    chamfer_mfma<2><<<2 * BB * 32 * 2, 256, 0, stream>>>(Aq, Bq, partial);
    chamfer_combine<2><<<TQ / 256, 256, 0, stream>>>(partial, yy, bsums);
  }
  chamfer_final<<<1, 256, 0, stream>>>(bsums, out, TQ / 256);
}

// Round 8
// 57.607 us; speedup vs baseline: 4.2529x; 1.0568x over previous
//
#include <hip/hip_runtime.h>

typedef _Float16 f16;
typedef f16 half8 __attribute__((ext_vector_type(8)));
typedef float f32x16 __attribute__((ext_vector_type(16)));

#define BB 8
#define NN 8192
#define SETPTS (BB * NN)   // 65536 points per set
#define NPTS (2 * SETPTS)  // 131072 total points
#define TQ NPTS            // total queries

// ---------------- prep: build fp16-split MFMA operands ----------------
// A-rep (query):  per coord (h,l,h,l); tail (1,1,0,0)
// B-rep (ref):    per coord (H,H,L,L) of -2y; tail (yy_h,yy_l,0,0)
// products per coord: hH + lH + hL + lL = (h+l)(H+L)  [exact in fp32 accum]
__global__ __launch_bounds__(256) void chamfer_prep(
    const float* __restrict__ preds, const float* __restrict__ gts,
    float* __restrict__ yy, half8* __restrict__ Aq, half8* __restrict__ Bq) {
  int idx = blockIdx.x * 256 + threadIdx.x;  // 0..NPTS-1
  int s = idx >> 16;                         // set: 0=preds, 1=gts
  int off = idx & (SETPTS - 1);
  const float* src = s ? gts : preds;
  float x0 = src[off * 3 + 0], x1 = src[off * 3 + 1], x2 = src[off * 3 + 2];

  f16 h0 = (f16)x0; f16 l0 = (f16)(x0 - (float)h0);
  f16 h1 = (f16)x1; f16 l1 = (f16)(x1 - (float)h1);
  f16 h2 = (f16)x2; f16 l2 = (f16)(x2 - (float)h2);

  float Y0 = -2.f * x0, Y1 = -2.f * x1, Y2 = -2.f * x2;
  f16 H0 = (f16)Y0; f16 L0 = (f16)(Y0 - (float)H0);
  f16 H1 = (f16)Y1; f16 L1 = (f16)(Y1 - (float)H1);
  f16 H2 = (f16)Y2; f16 L2 = (f16)(Y2 - (float)H2);

  float yv = x0 * x0 + x1 * x1 + x2 * x2;
  f16 yh = (f16)yv; f16 yl = (f16)(yv - (float)yh);

  f16 one = (f16)1.f, zz = (f16)0.f;
  half8 A0 = {h0, l0, h0, l0, h1, l1, h1, l1};
  half8 A1 = {h2, l2, h2, l2, one, one, zz, zz};
  half8 B0 = {H0, H0, L0, L0, H1, H1, L1, L1};
  half8 B1 = {H2, H2, L2, L2, yh, yl, zz, zz};

  Aq[idx * 2 + 0] = A0; Aq[idx * 2 + 1] = A1;
  Bq[idx * 2 + 0] = B0; Bq[idx * 2 + 1] = B1;
  yy[idx] = yv;
}

// ---------------- main: MFMA distance tiles + running per-query min ------
// Round-4 body with ONE change: depth-2 B-tile prefetch (t0..t3 rotation,
// load issued a full iteration before first use -> covers ~200-400cy L2
// latency). R=2, grid 1024 = exactly 4 blocks/CU. launch_bounds(256,4)
// gives a 128-VGPR budget; body needs ~80 -> no AGPR copies, no spill.
// Wave: 64 queries (2 A-frags). Block: 4 waves = 256 queries.
// A layout (32x32x16): row=lane&31, k=(lane>>5)*8+e.
// C/D layout: col=lane&31, row=(reg&3)+8*(reg>>2)+4*(lane>>5).
template <int R>
__global__ __launch_bounds__(256, 4) void chamfer_mfma(
    const half8* __restrict__ Aq, const half8* __restrict__ Bq,
    float* __restrict__ partial) {
  constexpr int NSTEP = NN / R / 32;  // b-tiles per block
  int bi = blockIdx.x;
  int r = bi % R;
  int qb = (bi / R) % 32;
  int b = (bi / (R * 32)) % BB;
  int dir = bi / (R * 32 * BB);

  int tid = threadIdx.x;
  int wid = tid >> 6;
  int l = tid & 63;
  int l31 = l & 31;
  int lh = l >> 5;

  const half8* Ap =
      Aq + ((size_t)(dir * BB + b) * NN + qb * 256 + wid * 64) * 2;
  half8 a0 = Ap[l31 * 2 + lh];
  half8 a1 = Ap[(32 + l31) * 2 + lh];

  const half8* Bl = Bq +
                    ((size_t)((1 - dir) * BB + b) * NN + r * (NN / R)) * 2 +
                    l31 * 2 + lh;

  f32x16 zero;
#pragma unroll
  for (int i = 0; i < 16; ++i) zero[i] = 0.f;
  f32x16 run0, run1;
#pragma unroll
  for (int i = 0; i < 16; ++i) { run0[i] = 3.4e38f; run1[i] = 3.4e38f; }

  half8 t0 = Bl[0];
  half8 t1 = Bl[64];
#pragma unroll 1
  for (int s = 0; s < NSTEP; s += 2) {
    half8 t2 = Bl[(size_t)(((s + 2) & (NSTEP - 1)) * 64)];  // wraps (dead at end)
    f32x16 o0 = __builtin_amdgcn_mfma_f32_32x32x16_f16(a0, t0, zero, 0, 0, 0);
    f32x16 o1 = __builtin_amdgcn_mfma_f32_32x32x16_f16(a1, t0, zero, 0, 0, 0);
#pragma unroll
    for (int i = 0; i < 16; ++i) {
      run0[i] = fminf(run0[i], o0[i]);
      run1[i] = fminf(run1[i], o1[i]);
    }
    half8 t3 = Bl[(size_t)(((s + 3) & (NSTEP - 1)) * 64)];
    f32x16 o2 = __builtin_amdgcn_mfma_f32_32x32x16_f16(a0, t1, zero, 0, 0, 0);
    f32x16 o3 = __builtin_amdgcn_mfma_f32_32x32x16_f16(a1, t1, zero, 0, 0, 0);
#pragma unroll
    for (int i = 0; i < 16; ++i) {
      run0[i] = fminf(run0[i], o2[i]);
      run1[i] = fminf(run1[i], o3[i]);
    }
    t0 = t2;
    t1 = t3;
  }

  // min over ref-columns (32 lanes within each half), write per-query
  size_t qflat = (size_t)(dir * BB + b) * NN + qb * 256 + wid * 64;
  float* pr = partial + (size_t)r * TQ + qflat;
#pragma unroll
  for (int i = 0; i < 16; ++i) {
    float v0 = run0[i], v1 = run1[i];
    v0 = fminf(v0, __shfl_xor(v0, 1));  v1 = fminf(v1, __shfl_xor(v1, 1));
    v0 = fminf(v0, __shfl_xor(v0, 2));  v1 = fminf(v1, __shfl_xor(v1, 2));
    v0 = fminf(v0, __shfl_xor(v0, 4));  v1 = fminf(v1, __shfl_xor(v1, 4));
    v0 = fminf(v0, __shfl_xor(v0, 8));  v1 = fminf(v1, __shfl_xor(v1, 8));
    v0 = fminf(v0, __shfl_xor(v0, 16)); v1 = fminf(v1, __shfl_xor(v1, 16));
    int row = (i & 3) + 8 * (i >> 2) + 4 * lh;
    if (l31 == i) {
      pr[row] = v0;
      pr[32 + row] = v1;
    }
  }
}

// ---------------- combine: min over R slices + query norm, block sum -----
template <int R>
__global__ __launch_bounds__(256) void chamfer_combine(
    const float* __restrict__ partial, const float* __restrict__ yy,
    float* __restrict__ bsums) {
  int q = blockIdx.x * 256 + threadIdx.x;
  float m = partial[q];
#pragma unroll
  for (int rr = 1; rr < R; ++rr) m = fminf(m, partial[(size_t)rr * TQ + q]);
  m += yy[q];
  __shared__ float s[256];
  s[threadIdx.x] = m;
  __syncthreads();
  for (int o = 128; o > 0; o >>= 1) {
    if (threadIdx.x < o) s[threadIdx.x] += s[threadIdx.x + o];
    __syncthreads();
  }
  if (threadIdx.x == 0) bsums[blockIdx.x] = s[0];
}

__global__ __launch_bounds__(256) void chamfer_final(
    const float* __restrict__ bsums, float* __restrict__ out, int n) {
  float v = 0.f;
  for (int i = threadIdx.x; i < n; i += 256) v += bsums[i];
  __shared__ float s[256];
  s[threadIdx.x] = v;
  __syncthreads();
  for (int o = 128; o > 0; o >>= 1) {
    if (threadIdx.x < o) s[threadIdx.x] += s[threadIdx.x + o];
    __syncthreads();
  }
  if (threadIdx.x == 0) out[0] = s[0];
}

extern "C" void kernel_launch(void* const* d_in, const int* in_sizes, int n_in,
                              void* d_out, int out_size, void* d_ws,
                              size_t ws_size, hipStream_t stream) {
  const float* preds = (const float*)d_in[0];
  const float* gts = (const float*)d_in[1];
  float* out = (float*)d_out;

  // ws layout (floats): partial[2*TQ] | bsums[1024] | yy[NPTS] | Aq | Bq
  float* partial = (float*)d_ws;
  float* bsums = partial + (size_t)2 * TQ;
  float* yy = bsums + 1024;
  half8* Aq = (half8*)(yy + NPTS);
  half8* Bq = Aq + (size_t)NPTS * 2;

  chamfer_prep<<<NPTS / 256, 256, 0, stream>>>(preds, gts, yy, Aq, Bq);
  chamfer_mfma<2><<<2 * BB * 32 * 2, 256, 0, stream>>>(Aq, Bq, partial);
  chamfer_combine<2><<<TQ / 256, 256, 0, stream>>>(partial, yy, bsums);
  chamfer_final<<<1, 256, 0, stream>>>(bsums, out, TQ / 256);
}

// Round 9
// 52.818 us; speedup vs baseline: 4.6386x; 1.0907x over previous
//
#include <hip/hip_runtime.h>

typedef _Float16 f16;
typedef f16 half8 __attribute__((ext_vector_type(8)));
typedef float f32x16 __attribute__((ext_vector_type(16)));

#define BB 8
#define NN 8192
#define SETPTS (BB * NN)   // 65536 points per set
#define NPTS (2 * SETPTS)  // 131072 total points
#define TQ NPTS            // total queries

__device__ __forceinline__ void gload_lds16(const void* g, void* l) {
  __builtin_amdgcn_global_load_lds(
      (const __attribute__((address_space(1))) void*)g,
      (__attribute__((address_space(3))) void*)l, 16, 0, 0);
}

// ---------------- prep: build fp16-split MFMA operands ----------------
// A-rep (query):  per coord (h,l,h,l); tail (1,1,0,0)
// B-rep (ref):    per coord (H,H,L,L) of -2y; tail (yy_h,yy_l,0,0)
// products per coord: hH + lH + hL + lL = (h+l)(H+L)  [exact in fp32 accum]
__global__ __launch_bounds__(256) void chamfer_prep(
    const float* __restrict__ preds, const float* __restrict__ gts,
    float* __restrict__ yy, half8* __restrict__ Aq, half8* __restrict__ Bq) {
  int idx = blockIdx.x * 256 + threadIdx.x;  // 0..NPTS-1
  int s = idx >> 16;                         // set: 0=preds, 1=gts
  int off = idx & (SETPTS - 1);
  const float* src = s ? gts : preds;
  float x0 = src[off * 3 + 0], x1 = src[off * 3 + 1], x2 = src[off * 3 + 2];

  f16 h0 = (f16)x0; f16 l0 = (f16)(x0 - (float)h0);
  f16 h1 = (f16)x1; f16 l1 = (f16)(x1 - (float)h1);
  f16 h2 = (f16)x2; f16 l2 = (f16)(x2 - (float)h2);

  float Y0 = -2.f * x0, Y1 = -2.f * x1, Y2 = -2.f * x2;
  f16 H0 = (f16)Y0; f16 L0 = (f16)(Y0 - (float)H0);
  f16 H1 = (f16)Y1; f16 L1 = (f16)(Y1 - (float)H1);
  f16 H2 = (f16)Y2; f16 L2 = (f16)(Y2 - (float)H2);

  float yv = x0 * x0 + x1 * x1 + x2 * x2;
  f16 yh = (f16)yv; f16 yl = (f16)(yv - (float)yh);

  f16 one = (f16)1.f, zz = (f16)0.f;
  half8 A0 = {h0, l0, h0, l0, h1, l1, h1, l1};
  half8 A1 = {h2, l2, h2, l2, one, one, zz, zz};
  half8 B0 = {H0, H0, L0, L0, H1, H1, L1, L1};
  half8 B1 = {H2, H2, L2, L2, yh, yl, zz, zz};

  Aq[idx * 2 + 0] = A0; Aq[idx * 2 + 1] = A1;
  Bq[idx * 2 + 0] = B0; Bq[idx * 2 + 1] = B1;
  yy[idx] = yv;
}

// ---------------- main: MFMA distance tiles + running per-query min ------
// Round-4 compute body; NEW: (1) B staged in LDS (16KB chunks, double-buffer)
// via global_load_lds with PRE-PERMUTED global source so LDS is in fragment
// read-order (lane l reads byte l*16: conflict-free); all 4 waves share the
// staged tiles -> 4x less L2/L3 traffic. (2) XCD swizzle: the 64 blocks of
// one (dir,b) panel land on one XCD -> panel L2-resident.
// Wave: 64 queries (2 A-frags). Block: 4 waves. R=2, grid 1024 = 4 blk/CU.
// A layout (32x32x16): row=lane&31, k=(lane>>5)*8+e.
// C/D layout: col=lane&31, row=(reg&3)+8*(reg>>2)+4*(lane>>5).
template <int R>
__global__ __launch_bounds__(256, 4) void chamfer_mfma(
    const half8* __restrict__ Aq, const half8* __restrict__ Bq,
    float* __restrict__ partial) {
  constexpr int NSTEP = NN / R / 32;  // 128 b-tiles per block
  constexpr int CH = 16;              // tiles per chunk (16 KB)
  constexpr int NCH = NSTEP / CH;     // 8 chunks
  __shared__ __align__(16) char lds[2][CH * 1024];

  // ---- XCD swizzle: xcd = bi & 7 (round-robin dispatch assumption) ----
  // 16 panels (dir,b), 2 panels per XCD, 32*R blocks per panel.
  int bi = blockIdx.x;
  int xcd = bi & 7;
  int idx = bi >> 3;                 // 0 .. 2*(32*R)-1
  int panel = xcd * 2 + (idx & 1);   // 0..15
  int dir = panel >> 3;
  int b = panel & 7;
  int sub = idx >> 1;                // 0 .. 32*R-1
  int qb = sub & 31;
  int r = sub >> 5;                  // 0..R-1 (R=2)

  int tid = threadIdx.x;
  int w = tid >> 6;
  int l = tid & 63;
  int l31 = l & 31;
  int lh = l >> 5;

  const half8* Ap =
      Aq + ((size_t)(dir * BB + b) * NN + qb * 256 + w * 64) * 2;
  half8 a0 = Ap[l31 * 2 + lh];
  half8 a1 = Ap[(32 + l31) * 2 + lh];

  // B panel for this block, as bytes. Tile t = 1024 B = 32 refs.
  const char* gpanel = (const char*)(Bq + ((size_t)((1 - dir) * BB + b) * NN +
                                           r * (NN / R)) * 2);
  // pre-permuted per-lane source offset: lane l stages the element it reads
  int perm = ((l & 31) * 2 + (l >> 5)) * 16;

  // wave w stages tiles [w*4, w*4+4) of each chunk
  auto stage = [&](int buf, int c) {
    const char* csrc = gpanel + (size_t)(c * CH + w * 4) * 1024 + perm;
    char* cdst = &lds[buf][w * 4 * 1024];
#pragma unroll
    for (int i = 0; i < 4; ++i)
      gload_lds16(csrc + i * 1024, cdst + i * 1024);
  };

  f32x16 zero;
#pragma unroll
  for (int i = 0; i < 16; ++i) zero[i] = 0.f;
  f32x16 run0, run1;
#pragma unroll
  for (int i = 0; i < 16; ++i) { run0[i] = 3.4e38f; run1[i] = 3.4e38f; }

  stage(0, 0);
  __syncthreads();  // drains vmcnt then barrier: chunk 0 resident

#pragma unroll 1
  for (int ch = 0; ch < NCH; ++ch) {
    int par = ch & 1;
    if (ch + 1 < NCH) stage(par ^ 1, ch + 1);  // async prefetch next chunk
    const half8* lb = (const half8*)&lds[par][0];
#pragma unroll 4
    for (int st = 0; st < CH; ++st) {
      half8 bt = lb[st * 64 + l];  // ds_read_b128, conflict-free
      f32x16 o0 = __builtin_amdgcn_mfma_f32_32x32x16_f16(a0, bt, zero, 0, 0, 0);
      f32x16 o1 = __builtin_amdgcn_mfma_f32_32x32x16_f16(a1, bt, zero, 0, 0, 0);
#pragma unroll
      for (int i = 0; i < 16; ++i) {
        run0[i] = fminf(run0[i], o0[i]);
        run1[i] = fminf(run1[i], o1[i]);
      }
    }
    __syncthreads();  // all reads of lds[par] done; prefetch drained
  }

  // min over ref-columns (32 lanes within each half), write per-query
  size_t qflat = (size_t)(dir * BB + b) * NN + qb * 256 + w * 64;
  float* pr = partial + (size_t)r * TQ + qflat;
#pragma unroll
  for (int i = 0; i < 16; ++i) {
    float v0 = run0[i], v1 = run1[i];
    v0 = fminf(v0, __shfl_xor(v0, 1));  v1 = fminf(v1, __shfl_xor(v1, 1));
    v0 = fminf(v0, __shfl_xor(v0, 2));  v1 = fminf(v1, __shfl_xor(v1, 2));
    v0 = fminf(v0, __shfl_xor(v0, 4));  v1 = fminf(v1, __shfl_xor(v1, 4));
    v0 = fminf(v0, __shfl_xor(v0, 8));  v1 = fminf(v1, __shfl_xor(v1, 8));
    v0 = fminf(v0, __shfl_xor(v0, 16)); v1 = fminf(v1, __shfl_xor(v1, 16));
    int row = (i & 3) + 8 * (i >> 2) + 4 * lh;
    if (l31 == i) {
      pr[row] = v0;
      pr[32 + row] = v1;
    }
  }
}

// ---------------- combine: min over R slices + query norm, block sum -----
template <int R>
__global__ __launch_bounds__(256) void chamfer_combine(
    const float* __restrict__ partial, const float* __restrict__ yy,
    float* __restrict__ bsums) {
  int q = blockIdx.x * 256 + threadIdx.x;
  float m = partial[q];
#pragma unroll
  for (int rr = 1; rr < R; ++rr) m = fminf(m, partial[(size_t)rr * TQ + q]);
  m += yy[q];
  __shared__ float s[256];
  s[threadIdx.x] = m;
  __syncthreads();
  for (int o = 128; o > 0; o >>= 1) {
    if (threadIdx.x < o) s[threadIdx.x] += s[threadIdx.x + o];
    __syncthreads();
  }
  if (threadIdx.x == 0) bsums[blockIdx.x] = s[0];
}

__global__ __launch_bounds__(256) void chamfer_final(
    const float* __restrict__ bsums, float* __restrict__ out, int n) {
  float v = 0.f;
  for (int i = threadIdx.x; i < n; i += 256) v += bsums[i];
  __shared__ float s[256];
  s[threadIdx.x] = v;
  __syncthreads();
  for (int o = 128; o > 0; o >>= 1) {
    if (threadIdx.x < o) s[threadIdx.x] += s[threadIdx.x + o];
    __syncthreads();
  }
  if (threadIdx.x == 0) out[0] = s[0];
}

extern "C" void kernel_launch(void* const* d_in, const int* in_sizes, int n_in,
                              void* d_out, int out_size, void* d_ws,
                              size_t ws_size, hipStream_t stream) {
  const float* preds = (const float*)d_in[0];
  const float* gts = (const float*)d_in[1];
  float* out = (float*)d_out;

  // ws layout (floats): partial[2*TQ] | bsums[1024] | yy[NPTS] | Aq | Bq
  float* partial = (float*)d_ws;
  float* bsums = partial + (size_t)2 * TQ;
  float* yy = bsums + 1024;
  half8* Aq = (half8*)(yy + NPTS);
  half8* Bq = Aq + (size_t)NPTS * 2;

  chamfer_prep<<<NPTS / 256, 256, 0, stream>>>(preds, gts, yy, Aq, Bq);
  chamfer_mfma<2><<<2 * BB * 32 * 2, 256, 0, stream>>>(Aq, Bq, partial);
  chamfer_combine<2><<<TQ / 256, 256, 0, stream>>>(partial, yy, bsums);
  chamfer_final<<<1, 256, 0, stream>>>(bsums, out, TQ / 256);
}